// Round 3
// baseline (4606.926 us; speedup 1.0000x reference)
//
#include <hip/hip_runtime.h>
#include <math.h>

#define BB   128      // batch
#define T    45
#define E    300
#define HH   1024
#define G4   4096
#define HW   196      // 14*14
#define NPX  (BB*HW)  // 25088
#define C0   1026
#define CM   128
#define CR   130
#define TCH  15       // X-chunk timesteps (45 = 3*15)

static __device__ __forceinline__ float sigm(float x) { return 1.f / (1.f + __expf(-x)); }

// ---------------- embedding gather: emb[t][b][e] = lookup[que[b][t]][e] ----------------
__global__ void k_embed(const int* __restrict__ que, const float* __restrict__ lookup,
                        float* __restrict__ emb) {
    int idx = blockIdx.x * 256 + threadIdx.x;
    if (idx >= T * BB * E) return;
    int e = idx % E;
    int n = idx / E;
    int b = n % BB;
    int t = n / BB;
    int q = que[b * T + t];
    emb[idx] = lookup[(size_t)q * E + e];
}

// ---------------- generic NT GEMM with optional K-split over blockIdx.z ----------------
// C[m][n] = sum_{k in [z*ksplit, min((z+1)*ksplit,K))} A[m][k]*Bw[n][k]; C += z*cstride.
template <int BM, int BN, int TM, int TN>
__global__ __launch_bounds__(256) void k_gemm_nt(
    const float* __restrict__ A, int lda,
    const float* __restrict__ Bw, int ldb,
    const float* __restrict__ add,           // may be null; ld assumed == ldc
    const float* __restrict__ bias,          // may be null
    float* __restrict__ C, int ldc,
    int M, int N, int K, int relu,
    int ksplit, size_t cstride) {
    constexpr int KT = 16;
    constexpr int TX = BN / TN;
    __shared__ float As[KT][BM + 4];
    __shared__ float Bs[KT][BN + 4];
    const int tid = threadIdx.x;
    const int tx = tid % TX, ty = tid / TX;
    const int r0 = blockIdx.x * BM, c0 = blockIdx.y * BN;
    const int koff = blockIdx.z * ksplit;
    const int kend = (koff + ksplit < K) ? koff + ksplit : K;
    C += (size_t)blockIdx.z * cstride;
    float acc[TM][TN] = {};
    for (int k0 = koff; k0 < kend; k0 += KT) {
#pragma unroll
        for (int l = tid; l < BM * KT; l += 256) {
            int m = l / KT, k = l % KT;
            int gm = r0 + m, gk = k0 + k;
            As[k][m] = (gm < M && gk < kend) ? A[(size_t)gm * lda + gk] : 0.f;
        }
#pragma unroll
        for (int l = tid; l < BN * KT; l += 256) {
            int n = l / KT, k = l % KT;
            int gn = c0 + n, gk = k0 + k;
            Bs[k][n] = (gn < N && gk < kend) ? Bw[(size_t)gn * ldb + gk] : 0.f;
        }
        __syncthreads();
#pragma unroll
        for (int k = 0; k < KT; ++k) {
            float ar[TM], br[TN];
#pragma unroll
            for (int i = 0; i < TM; ++i) ar[i] = As[k][ty * TM + i];
#pragma unroll
            for (int j = 0; j < TN; ++j) br[j] = Bs[k][tx * TN + j];
#pragma unroll
            for (int i = 0; i < TM; ++i)
#pragma unroll
                for (int j = 0; j < TN; ++j) acc[i][j] += ar[i] * br[j];
        }
        __syncthreads();
    }
#pragma unroll
    for (int i = 0; i < TM; ++i) {
        int gm = r0 + ty * TM + i;
        if (gm >= M) continue;
#pragma unroll
        for (int j = 0; j < TN; ++j) {
            int gn = c0 + tx * TN + j;
            if (gn >= N) continue;
            float v = acc[i][j];
            if (add) v += add[(size_t)gm * ldc + gn];
            if (bias) v += bias[gn];
            if (relu) v = fmaxf(v, 0.f);
            C[(size_t)gm * ldc + gn] = v;
        }
    }
}

// ---------------- bias sum: out[n] = bih[n] + bhh[n] ----------------
__global__ void k_biasadd(const float* __restrict__ bih, const float* __restrict__ bhh,
                          float* __restrict__ out) {
    int idx = blockIdx.x * 256 + threadIdx.x;
    if (idx < G4) out[idx] = bih[idx] + bhh[idx];
}

// ---------------- cell: gates = gx + sum(partials); PyTorch order i,f,g,o ----------------
__global__ void k_cell4(float* __restrict__ h, float* __restrict__ c,
                        const float* __restrict__ gx,
                        const float* __restrict__ p, size_t pstride,
                        int np, int first) {
    int idx = blockIdx.x * 256 + threadIdx.x;   // < BB*HH
    int b = idx >> 10, j = idx & 1023;
    size_t base = (size_t)b * G4 + j;
    float gi = gx[base], gf = gx[base + HH], gg = gx[base + 2 * HH], go = gx[base + 3 * HH];
    for (int q = 0; q < np; ++q) {
        const float* pp = p + (size_t)q * pstride;
        gi += pp[base];
        gf += pp[base + HH];
        gg += pp[base + 2 * HH];
        go += pp[base + 3 * HH];
    }
    float cp = first ? 0.f : c[idx];
    float cn = sigm(gf) * cp + sigm(gi) * tanhf(gg);
    c[idx] = cn;
    h[idx] = sigm(go) * tanhf(cn);
}

// ---------------- enc: l2norm(concat(hf, hb)) per batch row -> out[b][0..2047] ----------------
__global__ void k_enc(const float* __restrict__ hf, const float* __restrict__ hb,
                      float* __restrict__ out) {
    int b = blockIdx.x;
    int tid = threadIdx.x;  // 256
    float vals[8];
    float ss = 0.f;
#pragma unroll
    for (int i = 0; i < 8; ++i) {
        int j = i * 256 + tid;
        float v = (j < HH) ? hf[(size_t)b * HH + j] : hb[(size_t)b * HH + (j - HH)];
        vals[i] = v;
        ss += v * v;
    }
    __shared__ float red[256];
    red[tid] = ss;
    __syncthreads();
    for (int s = 128; s > 0; s >>= 1) {
        if (tid < s) red[tid] += red[tid + s];
        __syncthreads();
    }
    float scale = 1.f / fmaxf(sqrtf(red[0]), 1e-12f);
#pragma unroll
    for (int i = 0; i < 8; ++i) out[(size_t)b * 2048 + i * 256 + tid] = vals[i] * scale;
}

// ---------------- per-pixel sum of squares over 1024 channels (atomic partial) ----------------
__global__ void k_pixssq(const float* __restrict__ img, float* __restrict__ ssq) {
    int b = blockIdx.x >> 4;
    int cc = (blockIdx.x & 15) * 64;
    int p = threadIdx.x;
    if (p >= HW) return;
    const float* base = img + ((size_t)b * 1024 + cc) * HW + p;
    float acc = 0.f;
#pragma unroll 4
    for (int c = 0; c < 64; ++c) {
        float v = base[(size_t)c * HW];
        acc += v * v;
    }
    atomicAdd(&ssq[b * HW + p], acc);
}

__global__ void k_invn(float* __restrict__ ssq) {
    int i = blockIdx.x * 256 + threadIdx.x;
    if (i >= NPX) return;
    ssq[i] = 1.f / fmaxf(sqrtf(ssq[i]), 1e-12f);
}

// ---------------- weight packs for REG-B convs: Bpk[ocg][tap][k][16 oc] ----------------
__global__ void k_packB0(const float* __restrict__ w, float* __restrict__ o) {
    int idx = blockIdx.x * 256 + threadIdx.x;
    if (idx >= 8 * 9 * 1040 * 16) return;
    int oi = idx & 15;
    int r = idx >> 4;        // (ocg*9+tap)*1040 + c
    int c = r % 1040;
    int gt = r / 1040;       // ocg*9+tap
    int tap = gt % 9, ocg = gt / 9;
    o[idx] = (c < C0) ? w[((size_t)(ocg * 16 + oi) * C0 + c) * 9 + tap] : 0.f;
}
__global__ void k_packBpm(const float* __restrict__ w, float* __restrict__ o) {
    int idx = blockIdx.x * 256 + threadIdx.x;
    if (idx >= 8 * 9 * 128 * 16) return;
    int oi = idx & 15;
    int r = idx >> 4;
    int c = r % 128;
    int gt = r / 128;
    int tap = gt % 9, ocg = gt / 9;
    o[idx] = w[((size_t)(ocg * 16 + oi) * 128 + c) * 9 + tap];
}

// ---------------- conv0: lane = global pixel, split-K over z, atomicAdd epilogue ----------
__global__ __launch_bounds__(256) void k_conv0(const float* __restrict__ img,
                                               const float* __restrict__ invn,
                                               const float* __restrict__ wpk,
                                               const float* __restrict__ bias,
                                               float* __restrict__ out) {
    __shared__ float As[289][20];   // slot 288 = zero row
    const int tid = threadIdx.x;
    const int P0 = blockIdx.x * 256;
    const int g = P0 + tid;          // global pixel (98*256 = 25088)
    const int ocg = blockIdx.y;      // 0..7
    const int koff = blockIdx.z * 208;   // 5 chunks of 208 (K padded to 1040)
    const int p = g % HW;
    const int y = p / 14, x = p % 14;
    float acc[16] = {};
    if (tid < 16) As[288][tid] = 0.f;
    for (int k0 = koff; k0 < koff + 208; k0 += 16) {
        __syncthreads();
        for (int l = tid; l < 288 * 16; l += 256) {
            int s = l % 288, k = l / 288;
            int gp = P0 - 16 + s;
            float v = 0.f;
            if (gp >= 0 && gp < NPX) {
                int gk = k0 + k;
                int pp = gp % HW;
                if (gk < 1024) v = img[((size_t)(gp / HW) * 1024 + gk) * HW + pp] * invn[gp];
                else if (gk == 1024) v = (float)(pp / 14 - 7) * (1.f / 7.f);
                else if (gk == 1025) v = (float)(pp % 14 - 7) * (1.f / 7.f);
            }
            As[s][k] = v;
        }
        __syncthreads();
        for (int tap = 0; tap < 9; ++tap) {
            const int ky = tap / 3 - 1, kx = tap % 3 - 1;
            const int yy = y + ky, xx = x + kx;
            const int of = ((unsigned)yy < 14u && (unsigned)xx < 14u)
                               ? (tid + 16 + ky * 14 + kx) : 288;
            const float4* __restrict__ wq =
                (const float4*)wpk + ((size_t)(ocg * 9 + tap) * 1040 + k0) * 4;
            for (int kq = 0; kq < 4; ++kq) {
                float4 a4 = *(const float4*)&As[of][kq * 4];
                float av[4] = {a4.x, a4.y, a4.z, a4.w};
#pragma unroll
                for (int kk = 0; kk < 4; ++kk) {
                    float a = av[kk];
                    float4 w0 = wq[0], w1 = wq[1], w2 = wq[2], w3 = wq[3];
                    wq += 4;
                    acc[0]  += a * w0.x;  acc[1]  += a * w0.y;
                    acc[2]  += a * w0.z;  acc[3]  += a * w0.w;
                    acc[4]  += a * w1.x;  acc[5]  += a * w1.y;
                    acc[6]  += a * w1.z;  acc[7]  += a * w1.w;
                    acc[8]  += a * w2.x;  acc[9]  += a * w2.y;
                    acc[10] += a * w2.z;  acc[11] += a * w2.w;
                    acc[12] += a * w3.x;  acc[13] += a * w3.y;
                    acc[14] += a * w3.z;  acc[15] += a * w3.w;
                }
            }
        }
    }
    float* op = out + (size_t)g * CM + ocg * 16;
    const float* bp = bias + ocg * 16;
    const bool z0 = (blockIdx.z == 0);
#pragma unroll
    for (int i = 0; i < 16; ++i) atomicAdd(&op[i], acc[i] + (z0 ? bp[i] : 0.f));
}

// ---------------- 3x3 pad1 conv on pixel-major [NPX][128], split-K=2, atomic epilogue ----
__global__ __launch_bounds__(256) void k_conv_pm(const float* __restrict__ vin,
                                                 const float* __restrict__ wpk,
                                                 const float* __restrict__ bias,
                                                 float* __restrict__ out) {
    __shared__ float As[289][20];
    const int tid = threadIdx.x;
    const int P0 = blockIdx.x * 256;
    const int g = P0 + tid;
    const int ocg = blockIdx.y;
    const int koff = blockIdx.z * 64;
    const int p = g % HW;
    const int y = p / 14, x = p % 14;
    float acc[16] = {};
    if (tid < 16) As[288][tid] = 0.f;
    for (int k0 = koff; k0 < koff + 64; k0 += 16) {
        __syncthreads();
        for (int l = tid; l < 288 * 4; l += 256) {
            int s = l >> 2, kq = l & 3;
            int gp = P0 - 16 + s;
            float4 v;
            v.x = v.y = v.z = v.w = 0.f;
            if (gp >= 0 && gp < NPX) v = *(const float4*)&vin[(size_t)gp * CM + k0 + kq * 4];
            *(float4*)&As[s][kq * 4] = v;
        }
        __syncthreads();
        for (int tap = 0; tap < 9; ++tap) {
            const int ky = tap / 3 - 1, kx = tap % 3 - 1;
            const int yy = y + ky, xx = x + kx;
            const int of = ((unsigned)yy < 14u && (unsigned)xx < 14u)
                               ? (tid + 16 + ky * 14 + kx) : 288;
            const float4* __restrict__ wq =
                (const float4*)wpk + ((size_t)(ocg * 9 + tap) * 128 + k0) * 4;
            for (int kq = 0; kq < 4; ++kq) {
                float4 a4 = *(const float4*)&As[of][kq * 4];
                float av[4] = {a4.x, a4.y, a4.z, a4.w};
#pragma unroll
                for (int kk = 0; kk < 4; ++kk) {
                    float a = av[kk];
                    float4 w0 = wq[0], w1 = wq[1], w2 = wq[2], w3 = wq[3];
                    wq += 4;
                    acc[0]  += a * w0.x;  acc[1]  += a * w0.y;
                    acc[2]  += a * w0.z;  acc[3]  += a * w0.w;
                    acc[4]  += a * w1.x;  acc[5]  += a * w1.y;
                    acc[6]  += a * w1.z;  acc[7]  += a * w1.w;
                    acc[8]  += a * w2.x;  acc[9]  += a * w2.y;
                    acc[10] += a * w2.z;  acc[11] += a * w2.w;
                    acc[12] += a * w3.x;  acc[13] += a * w3.y;
                    acc[14] += a * w3.z;  acc[15] += a * w3.w;
                }
            }
        }
    }
    float* op = out + (size_t)g * CM + ocg * 16;
    const float* bp = bias + ocg * 16;
    const bool z0 = (blockIdx.z == 0);
#pragma unroll
    for (int i = 0; i < 16; ++i) atomicAdd(&op[i], acc[i] + (z0 ? bp[i] : 0.f));
}

// ---------------- BN train stats: sum & sumsq per channel ----------------
__global__ void k_bnstats(const float* __restrict__ x, float* __restrict__ stats) {
    int r0 = blockIdx.x * 224;  // 112 blocks * 224 rows = 25088
    int c = threadIdx.x & 127, rh = threadIdx.x >> 7;
    float s = 0.f, ss = 0.f;
    for (int r = r0 + rh; r < r0 + 224; r += 2) {
        float v = x[(size_t)r * CM + c];
        s += v;
        ss += v * v;
    }
    __shared__ float rs[256], rss[256];
    rs[threadIdx.x] = s;
    rss[threadIdx.x] = ss;
    __syncthreads();
    if (threadIdx.x < 128) {
        s = rs[threadIdx.x] + rs[threadIdx.x + 128];
        ss = rss[threadIdx.x] + rss[threadIdx.x + 128];
        atomicAdd(&stats[c], s);
        atomicAdd(&stats[128 + c], ss);
    }
}

__global__ void k_bnfinal(const float* __restrict__ stats, const float* __restrict__ g,
                          const float* __restrict__ b, float* __restrict__ scsh) {
    int c = threadIdx.x;
    if (c >= 128) return;
    float mean = stats[c] / (float)NPX;
    float var = stats[128 + c] / (float)NPX - mean * mean;
    float sc = g[c] * rsqrtf(var + 1e-5f);
    scsh[c] = sc;
    scsh[128 + c] = b[c] - mean * sc;
}

// ---------------- relu(bn(x)) (+addv) -> vinr[p][c] (stride 130) ----------------
__global__ void k_apply_cat(const float* __restrict__ x, const float* __restrict__ scsh,
                            const float* __restrict__ addv, float* __restrict__ vinr) {
    int idx = blockIdx.x * 256 + threadIdx.x;
    if (idx >= NPX * CM) return;
    int c = idx & 127;
    int p = idx >> 7;
    float v = fmaxf(x[idx] * scsh[c] + scsh[128 + c], 0.f);
    if (addv) v += addv[idx];
    vinr[(size_t)p * CR + c] = v;
}

__global__ void k_coords_r(float* __restrict__ vinr) {
    int p = blockIdx.x * 256 + threadIdx.x;
    if (p >= NPX) return;
    int pp = p % HW;
    int y = pp / 14, x = pp % 14;
    vinr[(size_t)p * CR + 128] = (float)(y - 7) * (1.f / 7.f);
    vinr[(size_t)p * CR + 129] = (float)(x - 7) * (1.f / 7.f);
}

// ---------------- final: relu(bn(x)) + v1, transpose to NCHW output ----------------
__global__ void k_final(const float* __restrict__ x, const float* __restrict__ scsh,
                        const float* __restrict__ addv, float* __restrict__ outv) {
    int idx = blockIdx.x * 256 + threadIdx.x;
    if (idx >= NPX * CM) return;
    int p = idx % HW;
    int o = (idx / HW) & 127;
    int b = idx / (HW * CM);
    size_t pm = ((size_t)b * HW + p) * CM + o;
    outv[idx] = fmaxf(x[pm] * scsh[o] + scsh[128 + o], 0.f) + addv[pm];
}

extern "C" void kernel_launch(void* const* d_in, const int* in_sizes, int n_in,
                              void* d_out, int out_size, void* d_ws, size_t ws_size,
                              hipStream_t stream) {
    const int* que = (const int*)d_in[0];
    const float* img = (const float*)d_in[1];
    const float* lookup = (const float*)d_in[2];
    const float* Wih_f = (const float*)d_in[3];
    const float* Whh_f = (const float*)d_in[4];
    const float* bih_f = (const float*)d_in[5];
    const float* bhh_f = (const float*)d_in[6];
    const float* Wih_b = (const float*)d_in[7];
    const float* Whh_b = (const float*)d_in[8];
    const float* bih_b = (const float*)d_in[9];
    const float* bhh_b = (const float*)d_in[10];
    const float* conv0_w = (const float*)d_in[11];
    const float* conv0_b = (const float*)d_in[12];
    const float* bn0_g = (const float*)d_in[13];
    const float* bn0_b = (const float*)d_in[14];
    const float* r1c1_w = (const float*)d_in[15];
    const float* r1c1_b = (const float*)d_in[16];
    const float* r1c2_w = (const float*)d_in[17];
    const float* r1c2_b = (const float*)d_in[18];
    const float* r1bn_g = (const float*)d_in[19];
    const float* r1bn_b = (const float*)d_in[20];
    const float* r2c1_w = (const float*)d_in[21];
    const float* r2c1_b = (const float*)d_in[22];
    const float* r2c2_w = (const float*)d_in[23];
    const float* r2c2_b = (const float*)d_in[24];
    const float* r2bn_g = (const float*)d_in[25];
    const float* r2bn_b = (const float*)d_in[26];
    float* out = (float*)d_out;

    float* ws = (float*)d_ws;
    // ---- LSTM region (dead once k_enc has run; image region overlays it) ----
    float* emb = ws;                         // 1,728,000
    float* Xc = emb + 1728000;               // 7,864,320  (15 x 128 x 4096)
    float* Xb = Xc + 7864320;                // 524,288
    float* part = Xb + 524288;               // 2,097,152  (4 x 128 x 4096)
    float* b4fp = part + 2097152;            // 4,096
    float* b4bp = b4fp + 4096;               // 4,096
    float* h = b4bp + 4096;                  // 131,072
    float* cbuf = h + 131072;                // 131,072
    float* hbb = cbuf + 131072;              // 131,072
    size_t lstm_end = (size_t)(hbb + 131072 - ws);
    // ---- image region (overlays LSTM region; stream order serializes) ----
    float* invn = ws;                        // 25,088
    float* wpk0 = invn + 25088;              // 1,198,080  (8 x 9 x 1040 x 16)
    float* wpk1 = wpk0 + 1198080;            // 147,456    (8 x 9 x 128 x 16)
    float* wpk2 = wpk1 + 147456;             // 147,456
    float* x0 = wpk2 + 147456;               // 3,211,264
    float* vinr = x0 + 3211264;              // 3,261,440
    float* v1 = vinr + 3261440;              // 3,211,264
    float* v2pre = v1 + 3211264;             // 3,211,264
    float* stats = v2pre + 3211264;          // 256
    float* scsh = stats + 256;               // 256
    size_t img_end = (size_t)(scsh + 256 - ws);
    size_t need = (lstm_end > img_end ? lstm_end : img_end) * 4;
    if (ws_size < need) return;  // insufficient workspace; fail loudly via validation

    auto cdiv = [](int a, int b) { return (a + b - 1) / b; };
    const size_t BG = (size_t)BB * G4;       // 524288

    // ================= LSTM branch =================
    k_embed<<<cdiv(T * BB * E, 256), 256, 0, stream>>>(que, lookup, emb);
    k_biasadd<<<16, 256, 0, stream>>>(bih_f, bhh_f, b4fp);
    k_biasadd<<<16, 256, 0, stream>>>(bih_b, bhh_b, b4bp);
    // backward LSTM: only position T-1 is used -> Xb = emb[T-1] @ Wih_b^T + bias; cell
    k_gemm_nt<64, 64, 4, 4><<<dim3(2, 64, 1), 256, 0, stream>>>(
        emb + (size_t)(T - 1) * BB * E, E, Wih_b, E, nullptr, b4bp, Xb, G4,
        BB, G4, E, 0, E, 0);
    k_cell4<<<512, 256, 0, stream>>>(hbb, cbuf, Xb, nullptr, 0, 0, 1);
    // forward LSTM: X chunks hoisted (not sequential); per-step split-K recurrent GEMM + cell
    for (int t = 0; t < T; ++t) {
        if (t % TCH == 0) {
            k_gemm_nt<64, 64, 4, 4><<<dim3(2 * TCH, 64, 1), 256, 0, stream>>>(
                emb + (size_t)t * BB * E, E, Wih_f, E, nullptr, b4fp, Xc, G4,
                TCH * BB, G4, E, 0, E, 0);
        }
        if (t > 0) {
            k_gemm_nt<32, 64, 2, 4><<<dim3(4, 64, 4), 256, 0, stream>>>(
                h, HH, Whh_f, HH, nullptr, nullptr, part, G4,
                BB, G4, HH, 0, 256, BG);
        }
        k_cell4<<<512, 256, 0, stream>>>(h, cbuf, Xc + (size_t)(t % TCH) * BG,
                                         part, BG, (t > 0) ? 4 : 0, t == 0);
    }
    k_enc<<<128, 256, 0, stream>>>(h, hbb, out);

    // ================= image branch (reuses LSTM workspace) =================
    hipMemsetAsync(invn, 0, NPX * 4, stream);
    k_pixssq<<<BB * 16, 256, 0, stream>>>(img, invn);
    k_invn<<<cdiv(NPX, 256), 256, 0, stream>>>(invn);
    k_packB0<<<cdiv(8 * 9 * 1040 * 16, 256), 256, 0, stream>>>(conv0_w, wpk0);
    k_packBpm<<<cdiv(8 * 9 * 128 * 16, 256), 256, 0, stream>>>(r1c2_w, wpk1);
    k_packBpm<<<cdiv(8 * 9 * 128 * 16, 256), 256, 0, stream>>>(r2c2_w, wpk2);

    hipMemsetAsync(x0, 0, (size_t)NPX * CM * 4, stream);
    k_conv0<<<dim3(98, 8, 5), 256, 0, stream>>>(img, invn, wpk0, conv0_b, x0);
    hipMemsetAsync(stats, 0, 256 * 4, stream);
    k_bnstats<<<112, 256, 0, stream>>>(x0, stats);
    k_bnfinal<<<1, 128, 0, stream>>>(stats, bn0_g, bn0_b, scsh);
    k_apply_cat<<<cdiv(NPX * CM, 256), 256, 0, stream>>>(x0, scsh, nullptr, vinr);
    k_coords_r<<<cdiv(NPX, 256), 256, 0, stream>>>(vinr);

    // resblock 1
    k_gemm_nt<64, 64, 4, 4><<<dim3(392, 2, 1), 256, 0, stream>>>(
        vinr, CR, r1c1_w, CR, nullptr, r1c1_b, v1, CM, NPX, CM, CR, 1, CR, 0);
    hipMemsetAsync(v2pre, 0, (size_t)NPX * CM * 4, stream);
    k_conv_pm<<<dim3(98, 8, 2), 256, 0, stream>>>(v1, wpk1, r1c2_b, v2pre);
    hipMemsetAsync(stats, 0, 256 * 4, stream);
    k_bnstats<<<112, 256, 0, stream>>>(v2pre, stats);
    k_bnfinal<<<1, 128, 0, stream>>>(stats, r1bn_g, r1bn_b, scsh);
    k_apply_cat<<<cdiv(NPX * CM, 256), 256, 0, stream>>>(v2pre, scsh, v1, vinr);

    // resblock 2
    k_gemm_nt<64, 64, 4, 4><<<dim3(392, 2, 1), 256, 0, stream>>>(
        vinr, CR, r2c1_w, CR, nullptr, r2c1_b, v1, CM, NPX, CM, CR, 1, CR, 0);
    hipMemsetAsync(v2pre, 0, (size_t)NPX * CM * 4, stream);
    k_conv_pm<<<dim3(98, 8, 2), 256, 0, stream>>>(v1, wpk2, r2c2_b, v2pre);
    hipMemsetAsync(stats, 0, 256 * 4, stream);
    k_bnstats<<<112, 256, 0, stream>>>(v2pre, stats);
    k_bnfinal<<<1, 128, 0, stream>>>(stats, r2bn_g, r2bn_b, scsh);
    k_final<<<cdiv(NPX * CM, 256), 256, 0, stream>>>(v2pre, scsh, v1, out + (size_t)BB * 2048);
}